// Round 8
// baseline (481.850 us; speedup 1.0000x reference)
//
#include <hip/hip_runtime.h>

#define BATCH 32
#define NUM_CLASS 20
#define NTOT 16128      // 768 + 3072 + 12288
#define N0 768
#define N1 3072
#define MAX_BOXES 150
#define SORT_N 8192
#define CAND_CAP 7600
#define TOPK_N 4096     // >= NUM_CLASS*MAX_BOXES = 3000
#define SCORE_THRESH 0.3f
#define IOU_THRESH 0.1f
#define NMS_W 1024
#define TOPK_W 1024

typedef unsigned long long u64;

// exp via double, rounded once to f32 (correctly-rounded center, minimizes
// distance to numpy's f32 exp). Rest of sigmoid stays stepwise-f32.
__device__ __forceinline__ float exp_f32cr(float x) { return (float)exp((double)x); }
__device__ __forceinline__ float sigm(float x) { return 1.0f / (1.0f + exp_f32cr(-x)); }

// iou with precomputed keep-area (ka computed once at keep time -> identical
// f32 value as ref's inline (kb.z-kb.x)*(kb.w-kb.y); comparison bit-exact).
__device__ __forceinline__ bool iou_rej2(float4 kb, float ka, float4 c4, float carea) {
    float ix1 = fmaxf(kb.x, c4.x), iy1 = fmaxf(kb.y, c4.y);
    float ix2 = fminf(kb.z, c4.z), iy2 = fminf(kb.w, c4.w);
    float inter = fmaxf(ix2 - ix1, 0.0f) * fmaxf(iy2 - iy1, 0.0f);
    return (inter / (ka + carea - inter)) > IOU_THRESH;   // exact ref math
}

// Bank-conflict swizzle: inject bits 4-7 into bits 0-3 (bijective involution).
__device__ __forceinline__ int phys_idx(int i) { return i ^ ((i >> 4) & 0xF); }

// ---------------------------------------------------------------------------
// Register-blocked bitonic sort core over nthreads*VPT u64 keys.
// Thread t owns contiguous logical elements [t*VPT, (t+1)*VPT) in r[].
// Caller fills lds[phys_idx(i)]; on return r[] sorted, lds stale.
// ---------------------------------------------------------------------------
template<int VPT>
__device__ __forceinline__ void bitonic_reg_core(u64 (&r)[VPT], u64* lds, int tid, int nthreads) {
    const int N = nthreads * VPT;
    #pragma unroll
    for (int e = 0; e < VPT; ++e) r[e] = lds[phys_idx(tid * VPT + e)];

    for (int k = 2; k <= N; k <<= 1) {
        int j = k >> 1;
        for (; j >= 64 * VPT; j >>= 1) {            // cross-wave: swizzled LDS
            __syncthreads();
            #pragma unroll
            for (int e = 0; e < VPT; ++e) lds[phys_idx(tid * VPT + e)] = r[e];
            __syncthreads();
            #pragma unroll
            for (int e = 0; e < VPT; ++e) {
                int i = tid * VPT + e;
                u64 q = lds[phys_idx(i ^ j)];
                bool takeMin = (((i & k) == 0) == ((i & j) == 0));
                bool less = r[e] < q;
                r[e] = (takeMin == less) ? r[e] : q;
            }
        }
        for (; j >= VPT; j >>= 1) {                 // in-wave: shfl_xor
            int ld = j / VPT;
            #pragma unroll
            for (int e = 0; e < VPT; ++e) {
                unsigned lo = (unsigned)r[e], hi = (unsigned)(r[e] >> 32);
                lo = (unsigned)__shfl_xor((int)lo, ld);
                hi = (unsigned)__shfl_xor((int)hi, ld);
                u64 q = ((u64)hi << 32) | lo;
                int i = tid * VPT + e;
                bool takeMin = (((i & k) == 0) == ((i & j) == 0));
                bool less = r[e] < q;
                r[e] = (takeMin == less) ? r[e] : q;
            }
        }
        for (; j >= 1; j >>= 1) {                   // in-thread: registers
            #pragma unroll
            for (int e = 0; e < VPT; ++e) {
                int p = e ^ j;
                if (p > e) {
                    int i = tid * VPT + e;
                    bool up = ((i & k) == 0);
                    u64 a = r[e], bkey = r[p];
                    if (up ? (a > bkey) : (a < bkey)) { r[e] = bkey; r[p] = a; }
                }
            }
        }
    }
}

// ---------------------------------------------------------------------------
// Kernel 1: decode -> corner boxes (B,N,4) + scores (B,C,N) class-major.
// ---------------------------------------------------------------------------
__global__ __launch_bounds__(256) void decode_kernel(
    const float* __restrict__ fm0, const float* __restrict__ fm1,
    const float* __restrict__ fm2, const float* __restrict__ anchors,
    float* __restrict__ boxes, float* __restrict__ scores)
{
    int t = blockIdx.x * 256 + threadIdx.x;
    if (t >= BATCH * NTOT) return;
    int b = t / NTOT, n = t % NTOT;
    const float* fm; int g, arow, local;
    if (n < N0)           { fm = fm0; g = 16; arow = 6; local = n; }
    else if (n < N0 + N1) { fm = fm1; g = 32; arow = 3; local = n - N0; }
    else                  { fm = fm2; g = 64; arow = 0; local = n - (N0 + N1); }
    int cell = local / 3, a = local % 3;
    int gy = cell / g, gx = cell % g;
    const float* p = fm + ((size_t)((b * g + gy) * g + gx) * 75 + (size_t)a * 25);
    float s = 512.0f / (float)g;   // power of two
    float cx = (sigm(p[0]) + (float)gx) * s;
    float cy = (sigm(p[1]) + (float)gy) * s;
    float w = exp_f32cr(p[2]) * anchors[(arow + a) * 2 + 0];
    float h = exp_f32cr(p[3]) * anchors[(arow + a) * 2 + 1];
    float conf = sigm(p[4]);
    float* bo = boxes + (size_t)t * 4;
    bo[0] = cx - w * 0.5f;
    bo[1] = cy - h * 0.5f;
    bo[2] = cx + w * 0.5f;
    bo[3] = cy + h * 0.5f;
    size_t sb = (size_t)b * NUM_CLASS * NTOT + (size_t)n;
    #pragma unroll
    for (int c = 0; c < NUM_CLASS; ++c)
        scores[sb + (size_t)c * NTOT] = conf * sigm(p[5 + c]);
}

// ---------------------------------------------------------------------------
// Kernel 2: MERGED per-(batch,class) sort + greedy scan.
// 16 waves compact + bitonic-sort 8192 keys in LDS; waves 1-15 exit; wave 0
// runs the round-6-proven serial greedy scan straight from LDS (shfl
// broadcast resolve, lane 0 sole LDS writer, __threadfence_block per chunk).
// Greedy == ref's 150-iter suppress loop (score desc, idx asc ties).
// ---------------------------------------------------------------------------
__global__ __launch_bounds__(NMS_W, 8) void nms_kernel(
    const float* __restrict__ boxes, const float* __restrict__ scores,
    int* __restrict__ kept_idx, float* __restrict__ kept_score)
{
    __shared__ u64 keys[SORT_N];             // 64 KB
    __shared__ float4 kept4[MAX_BOXES + 8];  // sentinel-padded to group of 8
    __shared__ float  karea_s[MAX_BOXES + 8];
    __shared__ unsigned scnt_s;

    const int tid = threadIdx.x;
    const int wlane = tid & 63;
    const int bc = blockIdx.x;            // b*NUM_CLASS + c
    const int b  = bc / NUM_CLASS;

    // sentinel (1e30)^4: inter=0, ka=0 -> iou = 0/carea = 0 <= thr (carea>0)
    for (int i = tid; i < MAX_BOXES + 8; i += NMS_W) {
        kept4[i] = make_float4(1e30f, 1e30f, 1e30f, 1e30f);
        karea_s[i] = 0.0f;
    }
    if (tid == 0) scnt_s = 0u;
    __syncthreads();

    // 1. compact candidates (score > 0.3); ballot-aggregated, swizzled store
    const float* sc = scores + (size_t)bc * NTOT;
    for (int n0 = 0; n0 < NTOT; n0 += NMS_W) {
        int n = n0 + tid;
        float s = (n < NTOT) ? sc[n] : -1.0f;
        bool pass = s > SCORE_THRESH;
        u64 m = __ballot(pass);
        unsigned base = 0;
        if (wlane == 0 && m) base = atomicAdd(&scnt_s, (unsigned)__popcll(m));
        base = __shfl(base, 0);
        if (pass) {
            unsigned pos = base + (unsigned)__popcll(m & ((1ull << wlane) - 1ull));
            if (pos < CAND_CAP) {
                unsigned sbits = ~__float_as_uint(s);
                keys[phys_idx((int)pos)] = ((u64)sbits << 32) | (unsigned)n;
            }
        }
    }
    __syncthreads();
    int cnt = (int)scnt_s; if (cnt > CAND_CAP) cnt = CAND_CAP;
    for (int i = cnt + tid; i < SORT_N; i += NMS_W) keys[phys_idx(i)] = ~0ull;
    __syncthreads();

    // 2. register-blocked bitonic sort + swizzled LDS writeback
    u64 r[SORT_N / NMS_W];
    bitonic_reg_core<SORT_N / NMS_W>(r, keys, tid, NMS_W);
    __syncthreads();                         // all core LDS reads done
    #pragma unroll
    for (int e = 0; e < SORT_N / NMS_W; ++e)
        keys[phys_idx(tid * (SORT_N / NMS_W) + e)] = r[e];
    __syncthreads();

    if (tid >= 64) return;                   // waves 1..15 done; wave 0 scans

    // 3. wave-serial greedy scan (round-6 form), keys from LDS
    const int lane = tid;
    const float* bbase = boxes + (size_t)b * NTOT * 4;
    const size_t obase = (size_t)bc * MAX_BOXES;
    int nk = 0;

    u64 key_cur = keys[phys_idx(lane)];
    int  cn_cur = (int)(key_cur & 0xffffffffull);
    // (unsigned)cn<NTOT guard: no-op on valid data; prevents OOB box loads if
    // rocprof replays against stale workspace.
    bool lv_cur = (lane < cnt) && ((unsigned)cn_cur < (unsigned)NTOT);
    float4 c4_cur = lv_cur ? *(const float4*)(bbase + (size_t)cn_cur * 4)
                           : make_float4(0.f, 0.f, 0.f, 0.f);

    for (int s0 = 0; s0 < cnt && nk < MAX_BOXES; s0 += 64) {
        // prefetch next chunk (key from LDS, box from global) under pre-check
        u64 key_nxt = keys[phys_idx(s0 + 64 + lane)];   // max 7679 < 8192, safe
        int  cn_nxt = (int)(key_nxt & 0xffffffffull);
        bool lv_nxt = ((s0 + 64 + lane) < cnt) && ((unsigned)cn_nxt < (unsigned)NTOT);
        float4 c4_nxt = lv_nxt ? *(const float4*)(bbase + (size_t)cn_nxt * 4)
                               : make_float4(0.f, 0.f, 0.f, 0.f);

        int state = 1;                    // 0=survivor, 1=rejected, 2=kept
        float cs = __uint_as_float(~(unsigned)(key_cur >> 32));
        float carea = (c4_cur.z - c4_cur.x) * (c4_cur.w - c4_cur.y);
        if (lv_cur) {
            state = 0;
            int nk8 = (nk + 7) & ~7;
            for (int kk = 0; kk < nk8; kk += 8) {   // 8 indep LDS streams
                bool rej = false;
                #pragma unroll
                for (int u = 0; u < 8; ++u)
                    rej |= iou_rej2(kept4[kk + u], karea_s[kk + u], c4_cur, carea);
                if (rej) { state = 1; break; }
            }
        }
        // wave-serial resolve: ballot + shfl broadcast, lane 0 sole LDS writer
        while (nk < MAX_BOXES) {
            u64 m = __ballot(state == 0);
            if (!m) break;
            int fi = (int)__builtin_ctzll(m);
            float4 kb;
            kb.x = __shfl(c4_cur.x, fi); kb.y = __shfl(c4_cur.y, fi);
            kb.z = __shfl(c4_cur.z, fi); kb.w = __shfl(c4_cur.w, fi);
            int   kn = __shfl(cn_cur, fi);
            float ks = __shfl(cs, fi);
            float ka = __shfl(carea, fi);
            if (lane == 0) {
                kept4[nk] = kb; karea_s[nk] = ka;
                kept_idx  [obase + nk] = kn;
                kept_score[obase + nk] = ks;
            }
            if (lane == fi) state = 2;
            else if (state == 0 && iou_rej2(kb, ka, c4_cur, carea)) state = 1;
            ++nk;
        }
        key_cur = key_nxt; cn_cur = cn_nxt; lv_cur = lv_nxt; c4_cur = c4_nxt;
        __threadfence_block();   // order lane0's kept4/karea writes before next pre-check
    }
    for (int kx = nk + lane; kx < MAX_BOXES; kx += 64) {
        kept_idx  [obase + kx] = -1;
        kept_score[obase + kx] = -1.0f;
    }
}

// ---------------------------------------------------------------------------
// Kernel 3: per-image top-150 over 3000 kept entries (ties: lower flat pos).
// ---------------------------------------------------------------------------
__global__ __launch_bounds__(TOPK_W) void topk_kernel(
    const float* __restrict__ boxes, const int* __restrict__ kept_idx,
    const float* __restrict__ kept_score, float* __restrict__ out)
{
    __shared__ u64 keys[TOPK_N];
    const int tid = threadIdx.x;
    const int b = blockIdx.x;
    const int FLAT = NUM_CLASS * MAX_BOXES;   // 3000

    for (int f = tid; f < TOPK_N; f += TOPK_W) {
        u64 key = ~0ull;
        if (f < FLAT) {
            int idx = kept_idx[(size_t)b * FLAT + f];
            float s = (idx >= 0) ? kept_score[(size_t)b * FLAT + f] : -1.0f;
            unsigned u = __float_as_uint(s);
            unsigned mm = (u & 0x80000000u) ? ~u : (u | 0x80000000u);
            key = ((u64)(~mm) << 32) | (unsigned)f;  // ascending = score desc, pos asc
        }
        keys[phys_idx(f)] = key;
    }
    __syncthreads();

    u64 r[TOPK_N / TOPK_W];
    bitonic_reg_core<TOPK_N / TOPK_W>(r, keys, tid, TOPK_W);

    __syncthreads();
    #pragma unroll
    for (int e = 0; e < TOPK_N / TOPK_W; ++e)
        keys[phys_idx(tid * (TOPK_N / TOPK_W) + e)] = r[e];
    __syncthreads();

    if (tid < MAX_BOXES) {
        u64 key = keys[phys_idx(tid)];
        int f = (int)(key & 0xffffffffull);
        float sc = -1.0f; int idx = -1;
        if (f < FLAT) {
            idx = kept_idx[(size_t)b * FLAT + f];
            if (idx >= 0) sc = kept_score[(size_t)b * FLAT + f];
        }
        bool ok = (idx >= 0) && (sc > 0.0f);
        float bx0 = -1.0f, bx1 = -1.0f, bx2 = -1.0f, bx3 = -1.0f;
        float lab = -1.0f;
        if (ok) {
            const float* bp = boxes + ((size_t)b * NTOT + idx) * 4;
            bx0 = bp[0]; bx1 = bp[1]; bx2 = bp[2]; bx3 = bp[3];
            lab = (float)(f / MAX_BOXES);
        } else {
            sc = -1.0f;
        }
        float* ob = out + ((size_t)b * MAX_BOXES + tid) * 4;
        ob[0] = bx0; ob[1] = bx1; ob[2] = bx2; ob[3] = bx3;
        out[(size_t)BATCH * MAX_BOXES * 4 + (size_t)b * MAX_BOXES + tid] = sc;
        out[(size_t)BATCH * MAX_BOXES * 5 + (size_t)b * MAX_BOXES + tid] = lab;
    }
}

extern "C" void kernel_launch(void* const* d_in, const int* in_sizes, int n_in,
                              void* d_out, int out_size, void* d_ws, size_t ws_size,
                              hipStream_t stream) {
    const float* fm0 = (const float*)d_in[0];
    const float* fm1 = (const float*)d_in[1];
    const float* fm2 = (const float*)d_in[2];
    const float* anchors = (const float*)d_in[3];
    float* out = (float*)d_out;

    // workspace carve (all 16B-aligned)
    float* boxes  = (float*)d_ws;                                   // B*N*4   (8.25 MB)
    float* scores = boxes + (size_t)BATCH * NTOT * 4;               // B*C*N   (41.3 MB)
    int*   kept_idx   = (int*)(scores + (size_t)BATCH * NUM_CLASS * NTOT);
    float* kept_score = (float*)(kept_idx + (size_t)BATCH * NUM_CLASS * MAX_BOXES);

    int total = BATCH * NTOT;
    decode_kernel<<<(total + 255) / 256, 256, 0, stream>>>(fm0, fm1, fm2, anchors, boxes, scores);
    nms_kernel<<<BATCH * NUM_CLASS, NMS_W, 0, stream>>>(boxes, scores, kept_idx, kept_score);
    topk_kernel<<<BATCH, TOPK_W, 0, stream>>>(boxes, kept_idx, kept_score, out);
}

// Round 9
// 388.440 us; speedup vs baseline: 1.2405x; 1.2405x over previous
//
#include <hip/hip_runtime.h>

#define BATCH 32
#define NUM_CLASS 20
#define NTOT 16128      // 768 + 3072 + 12288
#define N0 768
#define N1 3072
#define MAX_BOXES 150
#define SORT_N 8192
#define CAND_CAP 7600
#define TOPK_N 4096     // >= NUM_CLASS*MAX_BOXES = 3000
#define SCORE_THRESH 0.3f
#define IOU_THRESH 0.1f
#define NMS_W 1024
#define SCAN_W 256
#define TOPK_W 1024

typedef unsigned long long u64;

// exp via double, rounded once to f32 (correctly-rounded center, minimizes
// distance to numpy's f32 exp). Rest of sigmoid stays stepwise-f32.
__device__ __forceinline__ float exp_f32cr(float x) { return (float)exp((double)x); }
__device__ __forceinline__ float sigm(float x) { return 1.0f / (1.0f + exp_f32cr(-x)); }

// iou with precomputed keep-area (ka computed once at keep time -> identical
// f32 value as ref's inline (kb.z-kb.x)*(kb.w-kb.y); comparison bit-exact).
__device__ __forceinline__ bool iou_rej2(float4 kb, float ka, float4 c4, float carea) {
    float ix1 = fmaxf(kb.x, c4.x), iy1 = fmaxf(kb.y, c4.y);
    float ix2 = fminf(kb.z, c4.z), iy2 = fminf(kb.w, c4.w);
    float inter = fmaxf(ix2 - ix1, 0.0f) * fmaxf(iy2 - iy1, 0.0f);
    return (inter / (ka + carea - inter)) > IOU_THRESH;   // exact ref math
}

// Bank-conflict swizzle: inject bits 4-7 into bits 0-3 (bijective involution).
__device__ __forceinline__ int phys_idx(int i) { return i ^ ((i >> 4) & 0xF); }

// ---------------------------------------------------------------------------
// Register-blocked bitonic sort core over nthreads*VPT u64 keys.
// Thread t owns contiguous logical elements [t*VPT, (t+1)*VPT) in r[].
// Caller fills lds[phys_idx(i)]; on return r[] sorted, lds stale.
// ---------------------------------------------------------------------------
template<int VPT>
__device__ __forceinline__ void bitonic_reg_core(u64 (&r)[VPT], u64* lds, int tid, int nthreads) {
    const int N = nthreads * VPT;
    #pragma unroll
    for (int e = 0; e < VPT; ++e) r[e] = lds[phys_idx(tid * VPT + e)];

    for (int k = 2; k <= N; k <<= 1) {
        int j = k >> 1;
        for (; j >= 64 * VPT; j >>= 1) {            // cross-wave: swizzled LDS
            __syncthreads();
            #pragma unroll
            for (int e = 0; e < VPT; ++e) lds[phys_idx(tid * VPT + e)] = r[e];
            __syncthreads();
            #pragma unroll
            for (int e = 0; e < VPT; ++e) {
                int i = tid * VPT + e;
                u64 q = lds[phys_idx(i ^ j)];
                bool takeMin = (((i & k) == 0) == ((i & j) == 0));
                bool less = r[e] < q;
                r[e] = (takeMin == less) ? r[e] : q;
            }
        }
        for (; j >= VPT; j >>= 1) {                 // in-wave: shfl_xor
            int ld = j / VPT;
            #pragma unroll
            for (int e = 0; e < VPT; ++e) {
                unsigned lo = (unsigned)r[e], hi = (unsigned)(r[e] >> 32);
                lo = (unsigned)__shfl_xor((int)lo, ld);
                hi = (unsigned)__shfl_xor((int)hi, ld);
                u64 q = ((u64)hi << 32) | lo;
                int i = tid * VPT + e;
                bool takeMin = (((i & k) == 0) == ((i & j) == 0));
                bool less = r[e] < q;
                r[e] = (takeMin == less) ? r[e] : q;
            }
        }
        for (; j >= 1; j >>= 1) {                   // in-thread: registers
            #pragma unroll
            for (int e = 0; e < VPT; ++e) {
                int p = e ^ j;
                if (p > e) {
                    int i = tid * VPT + e;
                    bool up = ((i & k) == 0);
                    u64 a = r[e], bkey = r[p];
                    if (up ? (a > bkey) : (a < bkey)) { r[e] = bkey; r[p] = a; }
                }
            }
        }
    }
}

// ---------------------------------------------------------------------------
// Kernel 1: decode -> corner boxes (B,N,4) + scores (B,C,N) class-major.
// ---------------------------------------------------------------------------
__global__ __launch_bounds__(256) void decode_kernel(
    const float* __restrict__ fm0, const float* __restrict__ fm1,
    const float* __restrict__ fm2, const float* __restrict__ anchors,
    float* __restrict__ boxes, float* __restrict__ scores)
{
    int t = blockIdx.x * 256 + threadIdx.x;
    if (t >= BATCH * NTOT) return;
    int b = t / NTOT, n = t % NTOT;
    const float* fm; int g, arow, local;
    if (n < N0)           { fm = fm0; g = 16; arow = 6; local = n; }
    else if (n < N0 + N1) { fm = fm1; g = 32; arow = 3; local = n - N0; }
    else                  { fm = fm2; g = 64; arow = 0; local = n - (N0 + N1); }
    int cell = local / 3, a = local % 3;
    int gy = cell / g, gx = cell % g;
    const float* p = fm + ((size_t)((b * g + gy) * g + gx) * 75 + (size_t)a * 25);
    float s = 512.0f / (float)g;   // power of two
    float cx = (sigm(p[0]) + (float)gx) * s;
    float cy = (sigm(p[1]) + (float)gy) * s;
    float w = exp_f32cr(p[2]) * anchors[(arow + a) * 2 + 0];
    float h = exp_f32cr(p[3]) * anchors[(arow + a) * 2 + 1];
    float conf = sigm(p[4]);
    float* bo = boxes + (size_t)t * 4;
    bo[0] = cx - w * 0.5f;
    bo[1] = cy - h * 0.5f;
    bo[2] = cx + w * 0.5f;
    bo[3] = cy + h * 0.5f;
    size_t sb = (size_t)b * NUM_CLASS * NTOT + (size_t)n;
    #pragma unroll
    for (int c = 0; c < NUM_CLASS; ++c)
        scores[sb + (size_t)c * NTOT] = conf * sigm(p[5 + c]);
}

// ---------------------------------------------------------------------------
// Kernel 2a: per-(batch,class) compact + register-bitonic sort -> global.
// key = (~score_bits << 32) | idx : ascending == (score desc, idx asc),
// identical to jnp.argsort(-s) stable order. (Measured 179 us, r6.)
// ---------------------------------------------------------------------------
__global__ __launch_bounds__(NMS_W) void sort_kernel(
    const float* __restrict__ scores, u64* __restrict__ skeys,
    int* __restrict__ scnt_g)
{
    __shared__ u64 keys[SORT_N];          // 64 KB
    __shared__ unsigned scnt_s;

    const int tid = threadIdx.x;
    const int wlane = tid & 63;
    const int bc = blockIdx.x;            // b*NUM_CLASS + c

    if (tid == 0) scnt_s = 0u;
    __syncthreads();

    const float* sc = scores + (size_t)bc * NTOT;
    for (int n0 = 0; n0 < NTOT; n0 += NMS_W) {
        int n = n0 + tid;
        float s = (n < NTOT) ? sc[n] : -1.0f;
        bool pass = s > SCORE_THRESH;
        u64 m = __ballot(pass);
        unsigned base = 0;
        if (wlane == 0 && m) base = atomicAdd(&scnt_s, (unsigned)__popcll(m));
        base = __shfl(base, 0);
        if (pass) {
            unsigned pos = base + (unsigned)__popcll(m & ((1ull << wlane) - 1ull));
            if (pos < CAND_CAP) {
                unsigned sbits = ~__float_as_uint(s);
                keys[phys_idx((int)pos)] = ((u64)sbits << 32) | (unsigned)n;
            }
        }
    }
    __syncthreads();
    int cnt = (int)scnt_s; if (cnt > CAND_CAP) cnt = CAND_CAP;
    for (int i = cnt + tid; i < SORT_N; i += NMS_W) keys[phys_idx(i)] = ~0ull;
    __syncthreads();

    u64 r[SORT_N / NMS_W];
    bitonic_reg_core<SORT_N / NMS_W>(r, keys, tid, NMS_W);

    // direct register->global store: thread t owns [8t, 8t+8) (64B, coalesced)
    u64* ko = skeys + (size_t)bc * SORT_N;
    #pragma unroll
    for (int e = 0; e < SORT_N / NMS_W; ++e)
        ko[tid * (SORT_N / NMS_W) + e] = r[e];
    if (tid == 0) scnt_g[bc] = cnt;
}

// ---------------------------------------------------------------------------
// Kernel 2b: greedy scan, 4 WAVES (256 thr) per (b,c) problem.
// 256 candidates pre-checked per pass; resolve = round-3-proven barrier
// pattern (per-wave ballot -> LDS min-of-4 -> keeper broadcast), 2 cheap
// barriers per keep. Greedy == ref's 150-iter suppress loop.
// ---------------------------------------------------------------------------
__global__ __launch_bounds__(SCAN_W) void scan_kernel(
    const float* __restrict__ boxes, const u64* __restrict__ skeys,
    const int* __restrict__ scnt_g,
    int* __restrict__ kept_idx, float* __restrict__ kept_score)
{
    __shared__ float4 kept4[MAX_BOXES + 8];  // sentinel-padded to group of 8
    __shared__ float  karea_s[MAX_BOXES + 8];
    __shared__ int wmin_s[SCAN_W / 64];

    const int tid = threadIdx.x;
    const int wid = tid >> 6, wlane = tid & 63;
    const int bc = blockIdx.x;
    const int b  = bc / NUM_CLASS;

    // sentinel (1e30)^4: inter=0, ka=0 -> iou = 0/carea = 0 <= thr (carea>0)
    for (int i = tid; i < MAX_BOXES + 8; i += SCAN_W) {
        kept4[i] = make_float4(1e30f, 1e30f, 1e30f, 1e30f);
        karea_s[i] = 0.0f;
    }
    __syncthreads();

    const u64* keys = skeys + (size_t)bc * SORT_N;
    int cnt = scnt_g[bc]; if (cnt > CAND_CAP) cnt = CAND_CAP;
    const float* bbase = boxes + (size_t)b * NTOT * 4;
    const size_t obase = (size_t)bc * MAX_BOXES;
    int nk = 0;   // uniform across block

    for (int s0 = 0; s0 < cnt && nk < MAX_BOXES; s0 += SCAN_W) {
        int i = s0 + tid;                  // max 7855 < SORT_N (padded), safe
        u64 key = keys[i];
        int cn = (int)(key & 0xffffffffull);
        // (unsigned)cn<NTOT guard: no-op on valid data; prevents OOB box loads
        // if rocprof replays against stale workspace.
        bool lv = (i < cnt) && ((unsigned)cn < (unsigned)NTOT);
        float4 c4 = lv ? *(const float4*)(bbase + (size_t)cn * 4)
                       : make_float4(0.f, 0.f, 0.f, 0.f);
        float carea = (c4.z - c4.x) * (c4.w - c4.y);
        float cs = __uint_as_float(~(unsigned)(key >> 32));
        int state = lv ? 0 : 1;            // 0=survivor, 1=rejected, 2=kept

        if (state == 0) {                  // pre-check vs keeps at pass start
            int nk8 = (nk + 7) & ~7;
            for (int kk = 0; kk < nk8; kk += 8) {   // 8 indep LDS streams
                bool rej = false;
                #pragma unroll
                for (int u = 0; u < 8; ++u)
                    rej |= iou_rej2(kept4[kk + u], karea_s[kk + u], c4, carea);
                if (rej) { state = 1; break; }
            }
        }
        // resolve survivors in index order; one keep per iteration, 2 barriers
        while (nk < MAX_BOXES) {
            u64 m = __ballot(state == 0);
            if (wlane == 0) wmin_s[wid] = m ? (wid * 64 + (int)__builtin_ctzll(m)) : SCAN_W;
            __syncthreads();
            int fi = min(min(wmin_s[0], wmin_s[1]), min(wmin_s[2], wmin_s[3]));
            if (fi >= SCAN_W) break;       // uniform: no survivors left
            if (tid == fi) {               // keeper commits; LDS is the broadcast
                kept4[nk] = c4; karea_s[nk] = carea;
                kept_idx  [obase + nk] = cn;
                kept_score[obase + nk] = cs;
                state = 2;
            }
            __syncthreads();
            if (state == 0) {              // re-check vs the new keep only
                float4 kb = kept4[nk]; float ka = karea_s[nk];
                if (iou_rej2(kb, ka, c4, carea)) state = 1;
            }
            ++nk;
        }
        __syncthreads();                   // kept4/wmin_s quiesce before next pass
    }
    for (int kx = nk + tid; kx < MAX_BOXES; kx += SCAN_W) {
        kept_idx  [obase + kx] = -1;
        kept_score[obase + kx] = -1.0f;
    }
}

// ---------------------------------------------------------------------------
// Kernel 3: per-image top-150 over 3000 kept entries (ties: lower flat pos).
// ---------------------------------------------------------------------------
__global__ __launch_bounds__(TOPK_W) void topk_kernel(
    const float* __restrict__ boxes, const int* __restrict__ kept_idx,
    const float* __restrict__ kept_score, float* __restrict__ out)
{
    __shared__ u64 keys[TOPK_N];
    const int tid = threadIdx.x;
    const int b = blockIdx.x;
    const int FLAT = NUM_CLASS * MAX_BOXES;   // 3000

    for (int f = tid; f < TOPK_N; f += TOPK_W) {
        u64 key = ~0ull;
        if (f < FLAT) {
            int idx = kept_idx[(size_t)b * FLAT + f];
            float s = (idx >= 0) ? kept_score[(size_t)b * FLAT + f] : -1.0f;
            unsigned u = __float_as_uint(s);
            unsigned mm = (u & 0x80000000u) ? ~u : (u | 0x80000000u);
            key = ((u64)(~mm) << 32) | (unsigned)f;  // ascending = score desc, pos asc
        }
        keys[phys_idx(f)] = key;
    }
    __syncthreads();

    u64 r[TOPK_N / TOPK_W];
    bitonic_reg_core<TOPK_N / TOPK_W>(r, keys, tid, TOPK_W);

    __syncthreads();
    #pragma unroll
    for (int e = 0; e < TOPK_N / TOPK_W; ++e)
        keys[phys_idx(tid * (TOPK_N / TOPK_W) + e)] = r[e];
    __syncthreads();

    if (tid < MAX_BOXES) {
        u64 key = keys[phys_idx(tid)];
        int f = (int)(key & 0xffffffffull);
        float sc = -1.0f; int idx = -1;
        if (f < FLAT) {
            idx = kept_idx[(size_t)b * FLAT + f];
            if (idx >= 0) sc = kept_score[(size_t)b * FLAT + f];
        }
        bool ok = (idx >= 0) && (sc > 0.0f);
        float bx0 = -1.0f, bx1 = -1.0f, bx2 = -1.0f, bx3 = -1.0f;
        float lab = -1.0f;
        if (ok) {
            const float* bp = boxes + ((size_t)b * NTOT + idx) * 4;
            bx0 = bp[0]; bx1 = bp[1]; bx2 = bp[2]; bx3 = bp[3];
            lab = (float)(f / MAX_BOXES);
        } else {
            sc = -1.0f;
        }
        float* ob = out + ((size_t)b * MAX_BOXES + tid) * 4;
        ob[0] = bx0; ob[1] = bx1; ob[2] = bx2; ob[3] = bx3;
        out[(size_t)BATCH * MAX_BOXES * 4 + (size_t)b * MAX_BOXES + tid] = sc;
        out[(size_t)BATCH * MAX_BOXES * 5 + (size_t)b * MAX_BOXES + tid] = lab;
    }
}

extern "C" void kernel_launch(void* const* d_in, const int* in_sizes, int n_in,
                              void* d_out, int out_size, void* d_ws, size_t ws_size,
                              hipStream_t stream) {
    const float* fm0 = (const float*)d_in[0];
    const float* fm1 = (const float*)d_in[1];
    const float* fm2 = (const float*)d_in[2];
    const float* anchors = (const float*)d_in[3];
    float* out = (float*)d_out;

    // workspace carve (all 16B-aligned)
    float* boxes  = (float*)d_ws;                                   // B*N*4        (8.25 MB)
    float* scores = boxes + (size_t)BATCH * NTOT * 4;               // B*C*N        (41.3 MB)
    u64*   skeys  = (u64*)(scores + (size_t)BATCH * NUM_CLASS * NTOT); // B*C*SORT_N (40 MB)
    int*   scnt   = (int*)(skeys + (size_t)BATCH * NUM_CLASS * SORT_N);
    int*   kept_idx   = scnt + BATCH * NUM_CLASS;
    float* kept_score = (float*)(kept_idx + (size_t)BATCH * NUM_CLASS * MAX_BOXES);

    int total = BATCH * NTOT;
    decode_kernel<<<(total + 255) / 256, 256, 0, stream>>>(fm0, fm1, fm2, anchors, boxes, scores);
    sort_kernel<<<BATCH * NUM_CLASS, NMS_W, 0, stream>>>(scores, skeys, scnt);
    scan_kernel<<<BATCH * NUM_CLASS, SCAN_W, 0, stream>>>(boxes, skeys, scnt, kept_idx, kept_score);
    topk_kernel<<<BATCH, TOPK_W, 0, stream>>>(boxes, kept_idx, kept_score, out);
}